// Round 5
// baseline (590.263 us; speedup 1.0000x reference)
//
#include <hip/hip_runtime.h>
#include <hip/hip_bf16.h>

using bf16 = __hip_bfloat16;
typedef __attribute__((ext_vector_type(8))) short short8;
typedef __attribute__((ext_vector_type(4))) float floatx4;

#define GLDS16(g, l)                                                        \
  __builtin_amdgcn_global_load_lds(                                         \
      (const __attribute__((address_space(1))) void*)(g),                   \
      (__attribute__((address_space(3))) void*)(l), 16, 0, 0)

__device__ __forceinline__ short f2b(float x) {
  union { bf16 h; short s; } u;
  u.h = __float2bfloat16(x);
  return u.s;
}
__device__ __forceinline__ void st(float* p, float v) { *p = v; }
__device__ __forceinline__ void st(bf16* p, float v) { *p = __float2bfloat16(v); }

// ---- DPP cross-lane (stays off the LDS pipe) ------------------------------
template <int CTRL>
__device__ __forceinline__ float dpp_f(float x) {
  return __int_as_float(__builtin_amdgcn_update_dpp(
      0, __float_as_int(x), CTRL, 0xF, 0xF, true));
}
// reduce across the 16 lanes of a DPP row (l16 group)
__device__ __forceinline__ float red16_max(float x) {
  x = fmaxf(x, dpp_f<0xB1>(x));    // quad_perm [1,0,3,2]  (xor 1)
  x = fmaxf(x, dpp_f<0x4E>(x));    // quad_perm [2,3,0,1]  (xor 2)
  x = fmaxf(x, dpp_f<0x141>(x));   // row_half_mirror      (xor 7)
  x = fmaxf(x, dpp_f<0x140>(x));   // row_mirror           (xor 15)
  return x;
}
__device__ __forceinline__ float red16_sum(float x) {
  x += dpp_f<0xB1>(x);
  x += dpp_f<0x4E>(x);
  x += dpp_f<0x141>(x);
  x += dpp_f<0x140>(x);
  return x;
}

// ---------------------------------------------------------------------------
// fp32 -> bf16 cast, 8 elems/thread, coalesced.
// ---------------------------------------------------------------------------
__global__ void cast_kernel(const float* __restrict__ in, bf16* __restrict__ out,
                            long n) {
  long i = ((long)blockIdx.x * blockDim.x + threadIdx.x) * 8;
  if (i >= n) return;
  floatx4 a = *(const floatx4*)(in + i);
  floatx4 b = *(const floatx4*)(in + i + 4);
  short8 r;
  r[0] = f2b(a[0]); r[1] = f2b(a[1]); r[2] = f2b(a[2]); r[3] = f2b(a[3]);
  r[4] = f2b(b[0]); r[5] = f2b(b[1]); r[6] = f2b(b[2]); r[7] = f2b(b[3]);
  *(short8*)(out + i) = r;
}

// ---------------------------------------------------------------------------
// Shared GEMM core: acc[4][4] = A-tile(m0) x B-tile(n0)^T, m97 structure.
// ---------------------------------------------------------------------------
__device__ __forceinline__ void gemm_core(
    const bf16* __restrict__ A, const bf16* __restrict__ B, int K,
    long m0, long n0, bf16* As, bf16* Bs, floatx4 (&acc)[4][4])
{
  const int tid  = threadIdx.x;
  const int wave = tid >> 6;
  const int lane = tid & 63;
  const int quad = lane >> 4;
  const int l16  = lane & 15;
  const int wr = (wave >> 1) * 64;
  const int wc = (wave & 1) * 64;

  const int srow = wave * 32 + (lane >> 2);
  const int scol = (lane & 3) * 8;
  const bf16* Ag = A + (m0 + srow) * (long)K + scol;
  const bf16* Bg = B + (n0 + srow) * (long)K + scol;
  bf16* AsB = As + wave * 1024;
  bf16* BsB = Bs + wave * 1024;

#pragma unroll
  for (int mi = 0; mi < 4; mi++)
#pragma unroll
    for (int ni = 0; ni < 4; ni++) {
      floatx4 z = {0.f, 0.f, 0.f, 0.f};
      acc[mi][ni] = z;
    }

  for (int k0 = 0; k0 < K; k0 += 32) {
    GLDS16(Ag + k0,                AsB);
    GLDS16(Ag + 16 * (long)K + k0, AsB + 512);
    GLDS16(Bg + k0,                BsB);
    GLDS16(Bg + 16 * (long)K + k0, BsB + 512);
    __syncthreads();

    short8 a[4], b[4];
#pragma unroll
    for (int i = 0; i < 4; i++) {
      a[i] = *(const short8*)(As + (wr + i * 16 + l16) * 32 + quad * 8);
      b[i] = *(const short8*)(Bs + (wc + i * 16 + l16) * 32 + quad * 8);
    }
#pragma unroll
    for (int mi = 0; mi < 4; mi++)
#pragma unroll
      for (int ni = 0; ni < 4; ni++)
        acc[mi][ni] = __builtin_amdgcn_mfma_f32_16x16x32_bf16(
            a[mi], b[ni], acc[mi][ni], 0, 0, 0);
    __syncthreads();
  }
}

// ---------------------------------------------------------------------------
// Fused QKV projection. grid.y in [0,48): sel = y>>4 chooses weight/output.
// sel 0,1 (q,k): RoPE fused in epilogue. sel 2 (v): output transposed to
// v_t[b][h][d][s].   M=4096 (b*2048+s), N=2048 (h*128+d), K=2048.
// ---------------------------------------------------------------------------
__global__ __launch_bounds__(256) void qkv_gemm(
    const bf16* __restrict__ A,
    const bf16* __restrict__ B0, const bf16* __restrict__ B1,
    const bf16* __restrict__ B2,
    bf16* __restrict__ C0, bf16* __restrict__ C1, bf16* __restrict__ Cvt,
    int M, int N, int K)
{
  __shared__ bf16 As[128 * 32];
  __shared__ bf16 Bs[128 * 32];

  const int sel = blockIdx.y >> 4;
  const long m0 = (long)blockIdx.x * 128;
  const long n0 = (long)(blockIdx.y & 15) * 128;
  const bf16* B = (sel == 0) ? B0 : ((sel == 1) ? B1 : B2);

  floatx4 acc[4][4];
  gemm_core(A, B, K, m0, n0, As, Bs, acc);

  const int tid  = threadIdx.x;
  const int wave = tid >> 6;
  const int lane = tid & 63;
  const int quad = lane >> 4;
  const int l16  = lane & 15;
  const int wr = (wave >> 1) * 64;
  const int wc = (wave & 1) * 64;

  if (sel < 2) {
    // ---- RoPE epilogue: pairs (2p,2p+1) live in adjacent lanes (l16 bit0)
    bf16* C = (sel == 0) ? C0 : C1;
    const float sgn = (l16 & 1) ? 1.0f : -1.0f;
#pragma unroll
    for (int ni = 0; ni < 4; ni++) {
      const int n = (int)n0 + wc + ni * 16 + l16;   // h*128 + d
      const int p = (n & 127) >> 1;
      const float invf = exp2f(-(float)p * (13.287712379549449f / 64.0f));
#pragma unroll
      for (int mi = 0; mi < 4; mi++) {
        floatx4 v = acc[mi][ni];
        const int mbase = (int)m0 + wr + mi * 16 + quad * 4;
#pragma unroll
        for (int r = 0; r < 4; r++) {
          const float spos = (float)((mbase + r) & 2047);
          float sn, cs;
          __sincosf(spos * invf, &sn, &cs);
          const float pv = dpp_f<0xB1>(v[r]);       // partner of the pair
          const float outv = v[r] * cs + pv * (sgn * sn);
          st(&C[(long)(mbase + r) * N + n], outv);
        }
      }
    }
  } else {
    // ---- transposed V epilogue: v_t[((b*16+h)*128+d)*2048 + s], 4 s packed
#pragma unroll
    for (int ni = 0; ni < 4; ni++) {
      const int n = (int)n0 + wc + ni * 16 + l16;   // h*128 + d
      const int hh = n >> 7, d = n & 127;
#pragma unroll
      for (int mi = 0; mi < 4; mi++) {
        floatx4 v = acc[mi][ni];
        const int m = (int)m0 + wr + mi * 16 + quad * 4;
        const int bb = m >> 11, s = m & 2047;
        unsigned long long pk =
            (unsigned long long)(unsigned short)f2b(v[0]) |
            ((unsigned long long)(unsigned short)f2b(v[1]) << 16) |
            ((unsigned long long)(unsigned short)f2b(v[2]) << 32) |
            ((unsigned long long)(unsigned short)f2b(v[3]) << 48);
        *(unsigned long long*)(Cvt + ((long)((bb * 16 + hh) * 128 + d)) * 2048 + s) = pk;
      }
    }
  }
}

// ---------------------------------------------------------------------------
// Final projection GEMM (bf16 x bf16 -> fp32 out).
// ---------------------------------------------------------------------------
__global__ __launch_bounds__(256) void gemm_out(
    const bf16* __restrict__ A, const bf16* __restrict__ B,
    float* __restrict__ C, int M, int N, int K)
{
  __shared__ bf16 As[128 * 32];
  __shared__ bf16 Bs[128 * 32];
  const long m0 = (long)blockIdx.x * 128;
  const long n0 = (long)blockIdx.y * 128;

  floatx4 acc[4][4];
  gemm_core(A, B, K, m0, n0, As, Bs, acc);

  const int tid  = threadIdx.x;
  const int wave = tid >> 6;
  const int lane = tid & 63;
  const int quad = lane >> 4;
  const int l16  = lane & 15;
  const int wr = (wave >> 1) * 64;
  const int wc = (wave & 1) * 64;

#pragma unroll
  for (int mi = 0; mi < 4; mi++)
#pragma unroll
    for (int ni = 0; ni < 4; ni++) {
      floatx4 v = acc[mi][ni];
      const long row = m0 + wr + mi * 16 + quad * 4;
      const long col = n0 + wc + ni * 16 + l16;
#pragma unroll
      for (int r = 0; r < 4; r++)
        C[(row + r) * (long)N + col] = v[r];
    }
}

// ---------------------------------------------------------------------------
// Causal flash attention. Q-tile 128/block (wave owns 32 rows), kv-tile 64.
// K B-frags read DIRECTLY from global (L1/L2); V^T pre-transposed in global,
// staged to LDS with b128; softmax reductions via DPP; exp2 domain.
// q,k,o layout (B,S,H,hd); vt layout [b*H+h][d][s].
// ---------------------------------------------------------------------------
#define NEG_BIG (-30000.0f)

__global__ __launch_bounds__(256, 3) void flash_attn(
    const bf16* __restrict__ q, const bf16* __restrict__ k,
    const bf16* __restrict__ vt, bf16* __restrict__ o, int S)
{
  __shared__ bf16 Vt[128 * 72];      // V^T tile: [d][kv], stride 72
  __shared__ bf16 Ps[4][32 * 72];    // per-wave P scratch, stride 72

  const int tid  = threadIdx.x;
  const int wave = tid >> 6;
  const int lane = tid & 63;
  const int quad = lane >> 4;
  const int l16  = lane & 15;

  const int bh = blockIdx.x;
  const int b  = bh >> 4, h = bh & 15;
  const int q0 = ((int)gridDim.y - 1 - (int)blockIdx.y) * 128;  // heavy first

  const bf16* Qb = q + ((long)b * S * 16 + h) * 128;
  const bf16* Kb = k + ((long)b * S * 16 + h) * 128;
  const bf16* Vg = vt + (long)bh * 128 * S;       // [d][s]
  bf16*       Ob = o + ((long)b * S * 16 + h) * 128;

  // Q fragments: A[m=l16][k = kt*32 + quad*8 + j]
  short8 aq[2][4];
#pragma unroll
  for (int mi = 0; mi < 2; mi++)
#pragma unroll
    for (int kt = 0; kt < 4; kt++)
      aq[mi][kt] = *(const short8*)(
          Qb + (long)(q0 + wave * 32 + mi * 16 + l16) * 2048 + kt * 32 + quad * 8);

  float m_i[2][4], l_i[2][4];
  floatx4 oacc[2][8];
  const floatx4 zero4 = {0.f, 0.f, 0.f, 0.f};
#pragma unroll
  for (int mi = 0; mi < 2; mi++) {
#pragma unroll
    for (int r = 0; r < 4; r++) { m_i[mi][r] = NEG_BIG; l_i[mi][r] = 0.f; }
#pragma unroll
    for (int dt = 0; dt < 8; dt++) oacc[mi][dt] = zero4;
  }

  // exp2-domain scale: (1/sqrt(128)) * log2(e)
  const float SCL2 = 0.08838834764831845f * 1.4426950408889634f;
  const int wrow0 = q0 + wave * 32;

  for (int kt0 = 0; kt0 < q0 + 128; kt0 += 64) {
    __syncthreads();   // prior iteration's Vt reads complete

    // ---- stage V^T tile: 128 d-rows x 64 kv, b128 in and out ----
#pragma unroll
    for (int it = 0; it < 4; it++) {
      const int c = tid + it * 256;          // 0..1023
      const int row = c >> 3;                // d 0..127
      const int s0  = (c & 7) * 8;           // kv chunk
      *(short8*)(Vt + row * 72 + s0) =
          *(const short8*)(Vg + (long)row * S + kt0 + s0);
    }
    __syncthreads();

    if (kt0 <= wrow0 + 31) {   // wave-uniform skip of fully-masked tiles
      // ---- S = Q K^T, K frags straight from global ----
      floatx4 sc[2][4];
#pragma unroll
      for (int mi = 0; mi < 2; mi++)
#pragma unroll
        for (int nt = 0; nt < 4; nt++) sc[mi][nt] = zero4;
#pragma unroll
      for (int nt = 0; nt < 4; nt++) {
        short8 bk[4];
#pragma unroll
        for (int kt = 0; kt < 4; kt++)
          bk[kt] = *(const short8*)(
              Kb + (long)(kt0 + nt * 16 + l16) * 2048 + kt * 32 + quad * 8);
#pragma unroll
        for (int kt = 0; kt < 4; kt++) {
          sc[0][nt] = __builtin_amdgcn_mfma_f32_16x16x32_bf16(aq[0][kt], bk[kt], sc[0][nt], 0, 0, 0);
          sc[1][nt] = __builtin_amdgcn_mfma_f32_16x16x32_bf16(aq[1][kt], bk[kt], sc[1][nt], 0, 0, 0);
        }
      }

      const bool needmask = (kt0 + 63 > wrow0);
      float alpha[2][4];
#pragma unroll
      for (int mi = 0; mi < 2; mi++) {
#pragma unroll
        for (int r = 0; r < 4; r++) {
          const int qr = wrow0 + mi * 16 + quad * 4 + r;
          float mx = NEG_BIG;
          if (needmask) {
#pragma unroll
            for (int nt = 0; nt < 4; nt++) {
              const int kc = kt0 + nt * 16 + l16;
              float vsc = sc[mi][nt][r] * SCL2;
              vsc = (kc <= qr) ? vsc : NEG_BIG;
              sc[mi][nt][r] = vsc;
              mx = fmaxf(mx, vsc);
            }
          } else {
#pragma unroll
            for (int nt = 0; nt < 4; nt++) {
              float vsc = sc[mi][nt][r] * SCL2;
              sc[mi][nt][r] = vsc;
              mx = fmaxf(mx, vsc);
            }
          }
          mx = red16_max(mx);
          const float mnew = fmaxf(m_i[mi][r], mx);

          alpha[mi][r] = exp2f(m_i[mi][r] - mnew);
          float rs = 0.f;
#pragma unroll
          for (int nt = 0; nt < 4; nt++) {
            float p = exp2f(sc[mi][nt][r] - mnew);
            sc[mi][nt][r] = p;
            rs += p;
          }
          rs = red16_sum(rs);
          l_i[mi][r] = l_i[mi][r] * alpha[mi][r] + rs;
          m_i[mi][r] = mnew;
        }
      }

      // ---- P: C-layout -> A-layout via per-wave LDS round-trip ----
#pragma unroll
      for (int mi = 0; mi < 2; mi++)
#pragma unroll
        for (int nt = 0; nt < 4; nt++)
#pragma unroll
          for (int r = 0; r < 4; r++)
            Ps[wave][(mi * 16 + quad * 4 + r) * 72 + nt * 16 + l16] =
                __float2bfloat16(sc[mi][nt][r]);

      // rescale O
#pragma unroll
      for (int mi = 0; mi < 2; mi++)
#pragma unroll
        for (int dt = 0; dt < 8; dt++)
#pragma unroll
          for (int r = 0; r < 4; r++)
            oacc[mi][dt][r] *= alpha[mi][r];

      // ---- O += P V ----
#pragma unroll
      for (int ks = 0; ks < 2; ks++) {
        short8 ap0 = *(const short8*)(&Ps[wave][(l16) * 72 + ks * 32 + quad * 8]);
        short8 ap1 = *(const short8*)(&Ps[wave][(16 + l16) * 72 + ks * 32 + quad * 8]);
#pragma unroll
        for (int dt = 0; dt < 8; dt++) {
          short8 bv = *(const short8*)(Vt + (dt * 16 + l16) * 72 + ks * 32 + quad * 8);
          oacc[0][dt] = __builtin_amdgcn_mfma_f32_16x16x32_bf16(ap0, bv, oacc[0][dt], 0, 0, 0);
          oacc[1][dt] = __builtin_amdgcn_mfma_f32_16x16x32_bf16(ap1, bv, oacc[1][dt], 0, 0, 0);
        }
      }
    }
  }

  // ---- epilogue ----
#pragma unroll
  for (int mi = 0; mi < 2; mi++)
#pragma unroll
    for (int r = 0; r < 4; r++) {
      const float inv = 1.0f / l_i[mi][r];
      const long s = q0 + wave * 32 + mi * 16 + quad * 4 + r;
#pragma unroll
      for (int dt = 0; dt < 8; dt++)
        Ob[s * 2048 + dt * 16 + l16] = __float2bfloat16(oacc[mi][dt][r] * inv);
    }
}

// ---------------------------------------------------------------------------
extern "C" void kernel_launch(void* const* d_in, const int* in_sizes, int n_in,
                              void* d_out, int out_size, void* d_ws, size_t ws_size,
                              hipStream_t stream) {
  const float* x  = (const float*)d_in[0];
  const float* wq = (const float*)d_in[1];
  const float* wk = (const float*)d_in[2];
  const float* wv = (const float*)d_in[3];
  const float* wo = (const float*)d_in[4];
  float* out = (float*)d_out;

  const int B = 2, S = 2048, D = 2048, H = 16;
  const int M = B * S;                    // 4096
  const long tsz = (long)M * D;           // 8.39M elems
  const long wsz = (long)D * D;           // 4.19M elems

  if (ws_size < 4 * (size_t)tsz * sizeof(bf16)) return;   // 67 MB

  // ws: bf16 intermediates
  bf16* qb  = (bf16*)d_ws;
  bf16* kb  = qb + tsz;
  bf16* vtb = kb + tsz;                   // transposed V: [b][h][d][s]
  bf16* ab  = vtb + tsz;

  // d_out as scratch: xb (tsz) + wq' (wsz) + wk' (wsz) = exactly out bytes.
  bf16* xb  = (bf16*)d_out;
  bf16* wqb = xb + tsz;
  bf16* wkb = wqb + wsz;
  bf16* wvb = ab;                         // front half of ab (dead until flash)
  bf16* wob = qb;                         // qb dead after flash

  cast_kernel<<<(int)(tsz / 8 / 256), 256, 0, stream>>>(x,  xb,  tsz);
  cast_kernel<<<(int)(wsz / 8 / 256), 256, 0, stream>>>(wq, wqb, wsz);
  cast_kernel<<<(int)(wsz / 8 / 256), 256, 0, stream>>>(wk, wkb, wsz);
  cast_kernel<<<(int)(wsz / 8 / 256), 256, 0, stream>>>(wv, wvb, wsz);

  qkv_gemm<<<dim3(M / 128, 48), 256, 0, stream>>>(
      xb, wqb, wkb, wvb, qb, kb, vtb, M, D, D);

  flash_attn<<<dim3(B * H, S / 128), 256, 0, stream>>>(qb, kb, vtb, ab, S);

  cast_kernel<<<(int)(wsz / 8 / 256), 256, 0, stream>>>(wo, wob, wsz);
  gemm_out<<<dim3(M / 128, D / 128), 256, 0, stream>>>(ab, wob, out, M, D, D);
}

// Round 6
// 469.207 us; speedup vs baseline: 1.2580x; 1.2580x over previous
//
#include <hip/hip_runtime.h>
#include <hip/hip_bf16.h>

using bf16 = __hip_bfloat16;
typedef __attribute__((ext_vector_type(8))) short short8;
typedef __attribute__((ext_vector_type(4))) float floatx4;

#define GLDS16(g, l)                                                        \
  __builtin_amdgcn_global_load_lds(                                         \
      (const __attribute__((address_space(1))) void*)(g),                   \
      (__attribute__((address_space(3))) void*)(l), 16, 0, 0)

__device__ __forceinline__ short f2b(float x) {
  union { bf16 h; short s; } u;
  u.h = __float2bfloat16(x);
  return u.s;
}
__device__ __forceinline__ void st(float* p, float v) { *p = v; }
__device__ __forceinline__ void st(bf16* p, float v) { *p = __float2bfloat16(v); }

// ---- DPP cross-lane (stays off the LDS pipe) ------------------------------
template <int CTRL>
__device__ __forceinline__ float dpp_f(float x) {
  return __int_as_float(__builtin_amdgcn_update_dpp(
      0, __float_as_int(x), CTRL, 0xF, 0xF, true));
}
__device__ __forceinline__ float red16_max(float x) {
  x = fmaxf(x, dpp_f<0xB1>(x));    // quad_perm xor1
  x = fmaxf(x, dpp_f<0x4E>(x));    // quad_perm xor2
  x = fmaxf(x, dpp_f<0x141>(x));   // row_half_mirror
  x = fmaxf(x, dpp_f<0x140>(x));   // row_mirror
  return x;
}
__device__ __forceinline__ float red16_sum(float x) {
  x += dpp_f<0xB1>(x);
  x += dpp_f<0x4E>(x);
  x += dpp_f<0x141>(x);
  x += dpp_f<0x140>(x);
  return x;
}

// ---------------------------------------------------------------------------
// fp32 -> bf16 cast, 8 elems/thread, coalesced.
// ---------------------------------------------------------------------------
__global__ void cast_kernel(const float* __restrict__ in, bf16* __restrict__ out,
                            long n) {
  long i = ((long)blockIdx.x * blockDim.x + threadIdx.x) * 8;
  if (i >= n) return;
  floatx4 a = *(const floatx4*)(in + i);
  floatx4 b = *(const floatx4*)(in + i + 4);
  short8 r;
  r[0] = f2b(a[0]); r[1] = f2b(a[1]); r[2] = f2b(a[2]); r[3] = f2b(a[3]);
  r[4] = f2b(b[0]); r[5] = f2b(b[1]); r[6] = f2b(b[2]); r[7] = f2b(b[3]);
  *(short8*)(out + i) = r;
}

// ---------------------------------------------------------------------------
// Shared GEMM core: acc[4][4] = A-tile(m0) x B-tile(n0)^T, m97 structure.
// ---------------------------------------------------------------------------
__device__ __forceinline__ void gemm_core(
    const bf16* __restrict__ A, const bf16* __restrict__ B, int K,
    long m0, long n0, bf16* As, bf16* Bs, floatx4 (&acc)[4][4])
{
  const int tid  = threadIdx.x;
  const int wave = tid >> 6;
  const int lane = tid & 63;
  const int quad = lane >> 4;
  const int l16  = lane & 15;
  const int wr = (wave >> 1) * 64;
  const int wc = (wave & 1) * 64;

  const int srow = wave * 32 + (lane >> 2);
  const int scol = (lane & 3) * 8;
  const bf16* Ag = A + (m0 + srow) * (long)K + scol;
  const bf16* Bg = B + (n0 + srow) * (long)K + scol;
  bf16* AsB = As + wave * 1024;
  bf16* BsB = Bs + wave * 1024;

#pragma unroll
  for (int mi = 0; mi < 4; mi++)
#pragma unroll
    for (int ni = 0; ni < 4; ni++) {
      floatx4 z = {0.f, 0.f, 0.f, 0.f};
      acc[mi][ni] = z;
    }

  for (int k0 = 0; k0 < K; k0 += 32) {
    GLDS16(Ag + k0,                AsB);
    GLDS16(Ag + 16 * (long)K + k0, AsB + 512);
    GLDS16(Bg + k0,                BsB);
    GLDS16(Bg + 16 * (long)K + k0, BsB + 512);
    __syncthreads();

    short8 a[4], b[4];
#pragma unroll
    for (int i = 0; i < 4; i++) {
      a[i] = *(const short8*)(As + (wr + i * 16 + l16) * 32 + quad * 8);
      b[i] = *(const short8*)(Bs + (wc + i * 16 + l16) * 32 + quad * 8);
    }
#pragma unroll
    for (int mi = 0; mi < 4; mi++)
#pragma unroll
      for (int ni = 0; ni < 4; ni++)
        acc[mi][ni] = __builtin_amdgcn_mfma_f32_16x16x32_bf16(
            a[mi], b[ni], acc[mi][ni], 0, 0, 0);
    __syncthreads();
  }
}

// ---------------------------------------------------------------------------
// Fused QKV projection. grid.y in [0,48): sel = y>>4 chooses weight/output.
// sel 0,1 (q,k): RoPE fused in epilogue. sel 2 (v): output transposed to
// v_t[b][h][d][s].   M=4096 (b*2048+s), N=2048 (h*128+d), K=2048.
// ---------------------------------------------------------------------------
__global__ __launch_bounds__(256) void qkv_gemm(
    const bf16* __restrict__ A,
    const bf16* __restrict__ B0, const bf16* __restrict__ B1,
    const bf16* __restrict__ B2,
    bf16* __restrict__ C0, bf16* __restrict__ C1, bf16* __restrict__ Cvt,
    int M, int N, int K)
{
  __shared__ bf16 As[128 * 32];
  __shared__ bf16 Bs[128 * 32];

  const int sel = blockIdx.y >> 4;
  const long m0 = (long)blockIdx.x * 128;
  const long n0 = (long)(blockIdx.y & 15) * 128;
  const bf16* B = (sel == 0) ? B0 : ((sel == 1) ? B1 : B2);

  floatx4 acc[4][4];
  gemm_core(A, B, K, m0, n0, As, Bs, acc);

  const int tid  = threadIdx.x;
  const int wave = tid >> 6;
  const int lane = tid & 63;
  const int quad = lane >> 4;
  const int l16  = lane & 15;
  const int wr = (wave >> 1) * 64;
  const int wc = (wave & 1) * 64;

  if (sel < 2) {
    // RoPE epilogue: pairs (2p,2p+1) live in adjacent lanes (l16 bit0)
    bf16* C = (sel == 0) ? C0 : C1;
    const float sgn = (l16 & 1) ? 1.0f : -1.0f;
#pragma unroll
    for (int ni = 0; ni < 4; ni++) {
      const int n = (int)n0 + wc + ni * 16 + l16;   // h*128 + d
      const int p = (n & 127) >> 1;
      const float invf = exp2f(-(float)p * (13.287712379549449f / 64.0f));
#pragma unroll
      for (int mi = 0; mi < 4; mi++) {
        floatx4 v = acc[mi][ni];
        const int mbase = (int)m0 + wr + mi * 16 + quad * 4;
#pragma unroll
        for (int r = 0; r < 4; r++) {
          const float spos = (float)((mbase + r) & 2047);
          float sn, cs;
          __sincosf(spos * invf, &sn, &cs);
          const float pv = dpp_f<0xB1>(v[r]);       // pair partner
          const float outv = v[r] * cs + pv * (sgn * sn);
          st(&C[(long)(mbase + r) * N + n], outv);
        }
      }
    }
  } else {
    // transposed V epilogue: v_t[((b*16+h)*128+d)*2048 + s], 4 s packed
#pragma unroll
    for (int ni = 0; ni < 4; ni++) {
      const int n = (int)n0 + wc + ni * 16 + l16;   // h*128 + d
      const int hh = n >> 7, d = n & 127;
#pragma unroll
      for (int mi = 0; mi < 4; mi++) {
        floatx4 v = acc[mi][ni];
        const int m = (int)m0 + wr + mi * 16 + quad * 4;
        const int bb = m >> 11, s = m & 2047;
        unsigned long long pk =
            (unsigned long long)(unsigned short)f2b(v[0]) |
            ((unsigned long long)(unsigned short)f2b(v[1]) << 16) |
            ((unsigned long long)(unsigned short)f2b(v[2]) << 32) |
            ((unsigned long long)(unsigned short)f2b(v[3]) << 48);
        *(unsigned long long*)(Cvt + ((long)((bb * 16 + hh) * 128 + d)) * 2048 + s) = pk;
      }
    }
  }
}

// ---------------------------------------------------------------------------
// Final projection GEMM (bf16 x bf16 -> fp32 out).
// ---------------------------------------------------------------------------
__global__ __launch_bounds__(256) void gemm_out(
    const bf16* __restrict__ A, const bf16* __restrict__ B,
    float* __restrict__ C, int M, int N, int K)
{
  __shared__ bf16 As[128 * 32];
  __shared__ bf16 Bs[128 * 32];
  const long m0 = (long)blockIdx.x * 128;
  const long n0 = (long)blockIdx.y * 128;

  floatx4 acc[4][4];
  gemm_core(A, B, K, m0, n0, As, Bs, acc);

  const int tid  = threadIdx.x;
  const int wave = tid >> 6;
  const int lane = tid & 63;
  const int quad = lane >> 4;
  const int l16  = lane & 15;
  const int wr = (wave >> 1) * 64;
  const int wc = (wave & 1) * 64;

#pragma unroll
  for (int mi = 0; mi < 4; mi++)
#pragma unroll
    for (int ni = 0; ni < 4; ni++) {
      floatx4 v = acc[mi][ni];
      const long row = m0 + wr + mi * 16 + quad * 4;
      const long col = n0 + wc + ni * 16 + l16;
#pragma unroll
      for (int r = 0; r < 4; r++)
        C[(row + r) * (long)N + col] = v[r];
    }
}

// ---------------------------------------------------------------------------
// Causal flash attention. Q-tile 128/block (wave owns 32 rows), kv-tile 64.
// K AND V^T staged in LDS (revert of r5's K-from-global), with a register
// software pipeline: tile i+1's K/V global loads issue right after tile i's
// staging barrier and are consumed as LDS stores next iteration — global
// latency overlaps compute. DPP softmax, exp2 domain, heavy-tiles-first.
// q,k,o layout (B,S,H,hd); vt layout [b*H+h][d][s].
// ---------------------------------------------------------------------------
#define NEG_BIG (-30000.0f)

__global__ __launch_bounds__(256) void flash_attn(
    const bf16* __restrict__ q, const bf16* __restrict__ k,
    const bf16* __restrict__ vt, bf16* __restrict__ o, int S)
{
  __shared__ bf16 Ks[64 * 136];      // K tile row-major, stride 136
  __shared__ bf16 Vt[128 * 72];      // V^T tile: [d][kv], stride 72
  __shared__ bf16 Ps[4][32 * 72];    // per-wave P scratch, stride 72

  const int tid  = threadIdx.x;
  const int wave = tid >> 6;
  const int lane = tid & 63;
  const int quad = lane >> 4;
  const int l16  = lane & 15;

  const int bh = blockIdx.x;
  const int b  = bh >> 4, h = bh & 15;
  const int q0 = ((int)gridDim.y - 1 - (int)blockIdx.y) * 128;  // heavy first

  const bf16* Qb = q + ((long)b * S * 16 + h) * 128;
  const bf16* Kb = k + ((long)b * S * 16 + h) * 128;
  const bf16* Vg = vt + (long)bh * 128 * S;       // [d][s]
  bf16*       Ob = o + ((long)b * S * 16 + h) * 128;

  // staging maps (per-thread constants)
  int kr[4], kc[4], vr[4], vc[4];
#pragma unroll
  for (int it = 0; it < 4; it++) {
    const int c = tid + it * 256;
    kr[it] = c >> 4;  kc[it] = (c & 15) * 8;   // K: 64 rows x 128 d
    vr[it] = c >> 3;  vc[it] = (c & 7) * 8;    // V^T: 128 d x 64 kv
  }

  // Q fragments: A[m=l16][k = kt*32 + quad*8 + j]
  short8 aq[2][4];
#pragma unroll
  for (int mi = 0; mi < 2; mi++)
#pragma unroll
    for (int kt = 0; kt < 4; kt++)
      aq[mi][kt] = *(const short8*)(
          Qb + (long)(q0 + wave * 32 + mi * 16 + l16) * 2048 + kt * 32 + quad * 8);

  float m_i[2][4], l_i[2][4];
  floatx4 oacc[2][8];
  const floatx4 zero4 = {0.f, 0.f, 0.f, 0.f};
#pragma unroll
  for (int mi = 0; mi < 2; mi++) {
#pragma unroll
    for (int r = 0; r < 4; r++) { m_i[mi][r] = NEG_BIG; l_i[mi][r] = 0.f; }
#pragma unroll
    for (int dt = 0; dt < 8; dt++) oacc[mi][dt] = zero4;
  }

  const float SCL2 = 0.08838834764831845f * 1.4426950408889634f;  // scale*log2e
  const int wrow0 = q0 + wave * 32;
  const int last  = q0 + 64;          // final kt0

  // ---- prefetch tile 0 into registers ----
  short8 kreg[4], vreg[4];
#pragma unroll
  for (int it = 0; it < 4; it++) {
    kreg[it] = *(const short8*)(Kb + (long)kr[it] * 2048 + kc[it]);
    vreg[it] = *(const short8*)(Vg + (long)vr[it] * S + vc[it]);
  }

  for (int kt0 = 0; kt0 <= last; kt0 += 64) {
    __syncthreads();   // prior iteration's LDS reads complete

    // ---- stage from registers ----
#pragma unroll
    for (int it = 0; it < 4; it++) {
      *(short8*)(Ks + kr[it] * 136 + kc[it]) = kreg[it];
      *(short8*)(Vt + vr[it] * 72 + vc[it]) = vreg[it];
    }
    __syncthreads();

    // ---- prefetch tile i+1 (latency hidden behind compute below) ----
    if (kt0 < last) {
      const int n0 = kt0 + 64;
#pragma unroll
      for (int it = 0; it < 4; it++) {
        kreg[it] = *(const short8*)(Kb + (long)(n0 + kr[it]) * 2048 + kc[it]);
        vreg[it] = *(const short8*)(Vg + (long)vr[it] * S + n0 + vc[it]);
      }
    }

    if (kt0 <= wrow0 + 31) {   // wave-uniform skip of fully-masked tiles
      // ---- S = Q K^T (32 rows x 64 cols per wave) ----
      floatx4 sc[2][4];
#pragma unroll
      for (int mi = 0; mi < 2; mi++)
#pragma unroll
        for (int nt = 0; nt < 4; nt++) sc[mi][nt] = zero4;
#pragma unroll
      for (int nt = 0; nt < 4; nt++)
#pragma unroll
        for (int kt = 0; kt < 4; kt++) {
          short8 bk = *(const short8*)(Ks + (nt * 16 + l16) * 136 + kt * 32 + quad * 8);
          sc[0][nt] = __builtin_amdgcn_mfma_f32_16x16x32_bf16(aq[0][kt], bk, sc[0][nt], 0, 0, 0);
          sc[1][nt] = __builtin_amdgcn_mfma_f32_16x16x32_bf16(aq[1][kt], bk, sc[1][nt], 0, 0, 0);
        }

      const bool needmask = (kt0 + 63 > wrow0);
      float alpha[2][4];
#pragma unroll
      for (int mi = 0; mi < 2; mi++) {
#pragma unroll
        for (int r = 0; r < 4; r++) {
          const int qr = wrow0 + mi * 16 + quad * 4 + r;
          float mx = NEG_BIG;
          if (needmask) {
#pragma unroll
            for (int nt = 0; nt < 4; nt++) {
              const int kc2 = kt0 + nt * 16 + l16;
              float vsc = sc[mi][nt][r] * SCL2;
              vsc = (kc2 <= qr) ? vsc : NEG_BIG;
              sc[mi][nt][r] = vsc;
              mx = fmaxf(mx, vsc);
            }
          } else {
#pragma unroll
            for (int nt = 0; nt < 4; nt++) {
              float vsc = sc[mi][nt][r] * SCL2;
              sc[mi][nt][r] = vsc;
              mx = fmaxf(mx, vsc);
            }
          }
          mx = red16_max(mx);
          const float mnew = fmaxf(m_i[mi][r], mx);

          alpha[mi][r] = exp2f(m_i[mi][r] - mnew);
          float rs = 0.f;
#pragma unroll
          for (int nt = 0; nt < 4; nt++) {
            float p = exp2f(sc[mi][nt][r] - mnew);
            sc[mi][nt][r] = p;
            rs += p;
          }
          rs = red16_sum(rs);
          l_i[mi][r] = l_i[mi][r] * alpha[mi][r] + rs;
          m_i[mi][r] = mnew;
        }
      }

      // ---- P: C-layout -> A-layout via per-wave LDS round-trip ----
#pragma unroll
      for (int mi = 0; mi < 2; mi++)
#pragma unroll
        for (int nt = 0; nt < 4; nt++)
#pragma unroll
          for (int r = 0; r < 4; r++)
            Ps[wave][(mi * 16 + quad * 4 + r) * 72 + nt * 16 + l16] =
                __float2bfloat16(sc[mi][nt][r]);

      // rescale O
#pragma unroll
      for (int mi = 0; mi < 2; mi++)
#pragma unroll
        for (int dt = 0; dt < 8; dt++)
#pragma unroll
          for (int r = 0; r < 4; r++)
            oacc[mi][dt][r] *= alpha[mi][r];

      // ---- O += P V ----
#pragma unroll
      for (int ks = 0; ks < 2; ks++) {
        short8 ap0 = *(const short8*)(&Ps[wave][(l16) * 72 + ks * 32 + quad * 8]);
        short8 ap1 = *(const short8*)(&Ps[wave][(16 + l16) * 72 + ks * 32 + quad * 8]);
#pragma unroll
        for (int dt = 0; dt < 8; dt++) {
          short8 bv = *(const short8*)(Vt + (dt * 16 + l16) * 72 + ks * 32 + quad * 8);
          oacc[0][dt] = __builtin_amdgcn_mfma_f32_16x16x32_bf16(ap0, bv, oacc[0][dt], 0, 0, 0);
          oacc[1][dt] = __builtin_amdgcn_mfma_f32_16x16x32_bf16(ap1, bv, oacc[1][dt], 0, 0, 0);
        }
      }
    }
  }

  // ---- epilogue ----
#pragma unroll
  for (int mi = 0; mi < 2; mi++)
#pragma unroll
    for (int r = 0; r < 4; r++) {
      const float inv = 1.0f / l_i[mi][r];
      const long s = q0 + wave * 32 + mi * 16 + quad * 4 + r;
#pragma unroll
      for (int dt = 0; dt < 8; dt++)
        Ob[s * 2048 + dt * 16 + l16] = __float2bfloat16(oacc[mi][dt][r] * inv);
    }
}

// ---------------------------------------------------------------------------
extern "C" void kernel_launch(void* const* d_in, const int* in_sizes, int n_in,
                              void* d_out, int out_size, void* d_ws, size_t ws_size,
                              hipStream_t stream) {
  const float* x  = (const float*)d_in[0];
  const float* wq = (const float*)d_in[1];
  const float* wk = (const float*)d_in[2];
  const float* wv = (const float*)d_in[3];
  const float* wo = (const float*)d_in[4];
  float* out = (float*)d_out;

  const int B = 2, S = 2048, D = 2048, H = 16;
  const int M = B * S;                    // 4096
  const long tsz = (long)M * D;           // 8.39M elems
  const long wsz = (long)D * D;           // 4.19M elems

  if (ws_size < 4 * (size_t)tsz * sizeof(bf16)) return;   // 67 MB

  bf16* qb  = (bf16*)d_ws;
  bf16* kb  = qb + tsz;
  bf16* vtb = kb + tsz;                   // transposed V: [b][h][d][s]
  bf16* ab  = vtb + tsz;

  // d_out as scratch: xb (tsz) + wq' (wsz) + wk' (wsz) = exactly out bytes.
  bf16* xb  = (bf16*)d_out;
  bf16* wqb = xb + tsz;
  bf16* wkb = wqb + wsz;
  bf16* wvb = ab;                         // front half of ab (dead until flash)
  bf16* wob = qb;                         // qb dead after flash

  cast_kernel<<<(int)(tsz / 8 / 256), 256, 0, stream>>>(x,  xb,  tsz);
  cast_kernel<<<(int)(wsz / 8 / 256), 256, 0, stream>>>(wq, wqb, wsz);
  cast_kernel<<<(int)(wsz / 8 / 256), 256, 0, stream>>>(wk, wkb, wsz);
  cast_kernel<<<(int)(wsz / 8 / 256), 256, 0, stream>>>(wv, wvb, wsz);

  qkv_gemm<<<dim3(M / 128, 48), 256, 0, stream>>>(
      xb, wqb, wkb, wvb, qb, kb, vtb, M, D, D);

  flash_attn<<<dim3(B * H, S / 128), 256, 0, stream>>>(qb, kb, vtb, ab, S);

  cast_kernel<<<(int)(wsz / 8 / 256), 256, 0, stream>>>(wo, wob, wsz);
  gemm_out<<<dim3(M / 128, D / 128), 256, 0, stream>>>(ab, wob, out, M, D, D);
}

// Round 7
// 463.827 us; speedup vs baseline: 1.2726x; 1.0116x over previous
//
#include <hip/hip_runtime.h>
#include <hip/hip_bf16.h>

using bf16 = __hip_bfloat16;
typedef __attribute__((ext_vector_type(8))) short short8;
typedef __attribute__((ext_vector_type(4))) float floatx4;
typedef __attribute__((ext_vector_type(2))) float floatx2;

#define GLDS16(g, l)                                                        \
  __builtin_amdgcn_global_load_lds(                                         \
      (const __attribute__((address_space(1))) void*)(g),                   \
      (__attribute__((address_space(3))) void*)(l), 16, 0, 0)

__device__ __forceinline__ short f2b(float x) {
  union { bf16 h; short s; } u;
  u.h = __float2bfloat16(x);
  return u.s;
}
__device__ __forceinline__ void st(float* p, float v) { *p = v; }
__device__ __forceinline__ void st(bf16* p, float v) { *p = __float2bfloat16(v); }

// ---- DPP cross-lane (stays off the LDS pipe) ------------------------------
template <int CTRL>
__device__ __forceinline__ float dpp_f(float x) {
  return __int_as_float(__builtin_amdgcn_update_dpp(
      0, __float_as_int(x), CTRL, 0xF, 0xF, true));
}
__device__ __forceinline__ float red16_max(float x) {
  x = fmaxf(x, dpp_f<0xB1>(x));    // quad_perm xor1
  x = fmaxf(x, dpp_f<0x4E>(x));    // quad_perm xor2
  x = fmaxf(x, dpp_f<0x141>(x));   // row_half_mirror
  x = fmaxf(x, dpp_f<0x140>(x));   // row_mirror
  return x;
}
__device__ __forceinline__ float red16_sum(float x) {
  x += dpp_f<0xB1>(x);
  x += dpp_f<0x4E>(x);
  x += dpp_f<0x141>(x);
  x += dpp_f<0x140>(x);
  return x;
}

// ---------------------------------------------------------------------------
// fp32 -> bf16 cast, 8 elems/thread, coalesced.
// ---------------------------------------------------------------------------
__global__ void cast_kernel(const float* __restrict__ in, bf16* __restrict__ out,
                            long n) {
  long i = ((long)blockIdx.x * blockDim.x + threadIdx.x) * 8;
  if (i >= n) return;
  floatx4 a = *(const floatx4*)(in + i);
  floatx4 b = *(const floatx4*)(in + i + 4);
  short8 r;
  r[0] = f2b(a[0]); r[1] = f2b(a[1]); r[2] = f2b(a[2]); r[3] = f2b(a[3]);
  r[4] = f2b(b[0]); r[5] = f2b(b[1]); r[6] = f2b(b[2]); r[7] = f2b(b[3]);
  *(short8*)(out + i) = r;
}

// ---------------------------------------------------------------------------
// RoPE cos/sin table: tab[s*64+p] = {cos(s*invf(p)), sin(s*invf(p))}.
// One-time precompute (precise sincosf), 2048*64 entries = 1 MB.
// ---------------------------------------------------------------------------
__global__ void rope_tab_kernel(floatx2* __restrict__ tab) {
  const int t = blockIdx.x * blockDim.x + threadIdx.x;   // [0, 131072)
  const int s = t >> 6, p = t & 63;
  const float invf = exp2f(-(float)p * (13.287712379549449f / 64.0f));
  float sn, cs;
  sincosf((float)s * invf, &sn, &cs);
  floatx2 e; e[0] = cs; e[1] = sn;
  tab[t] = e;
}

// ---------------------------------------------------------------------------
// Shared GEMM core: acc[4][4] = A-tile(m0) x B-tile(n0)^T, m97 structure.
// ---------------------------------------------------------------------------
__device__ __forceinline__ void gemm_core(
    const bf16* __restrict__ A, const bf16* __restrict__ B, int K,
    long m0, long n0, bf16* As, bf16* Bs, floatx4 (&acc)[4][4])
{
  const int tid  = threadIdx.x;
  const int wave = tid >> 6;
  const int lane = tid & 63;
  const int quad = lane >> 4;
  const int l16  = lane & 15;
  const int wr = (wave >> 1) * 64;
  const int wc = (wave & 1) * 64;

  const int srow = wave * 32 + (lane >> 2);
  const int scol = (lane & 3) * 8;
  const bf16* Ag = A + (m0 + srow) * (long)K + scol;
  const bf16* Bg = B + (n0 + srow) * (long)K + scol;
  bf16* AsB = As + wave * 1024;
  bf16* BsB = Bs + wave * 1024;

#pragma unroll
  for (int mi = 0; mi < 4; mi++)
#pragma unroll
    for (int ni = 0; ni < 4; ni++) {
      floatx4 z = {0.f, 0.f, 0.f, 0.f};
      acc[mi][ni] = z;
    }

  for (int k0 = 0; k0 < K; k0 += 32) {
    GLDS16(Ag + k0,                AsB);
    GLDS16(Ag + 16 * (long)K + k0, AsB + 512);
    GLDS16(Bg + k0,                BsB);
    GLDS16(Bg + 16 * (long)K + k0, BsB + 512);
    __syncthreads();

    short8 a[4], b[4];
#pragma unroll
    for (int i = 0; i < 4; i++) {
      a[i] = *(const short8*)(As + (wr + i * 16 + l16) * 32 + quad * 8);
      b[i] = *(const short8*)(Bs + (wc + i * 16 + l16) * 32 + quad * 8);
    }
#pragma unroll
    for (int mi = 0; mi < 4; mi++)
#pragma unroll
      for (int ni = 0; ni < 4; ni++)
        acc[mi][ni] = __builtin_amdgcn_mfma_f32_16x16x32_bf16(
            a[mi], b[ni], acc[mi][ni], 0, 0, 0);
    __syncthreads();
  }
}

// ---------------------------------------------------------------------------
// Fused QKV projection. grid.y in [0,48): sel = y>>4 chooses weight/output.
// sel 0,1 (q,k): RoPE fused in epilogue via precomputed cos/sin table.
// sel 2 (v): output transposed to v_t[b][h][d][s].
// M=4096 (b*2048+s), N=2048 (h*128+d), K=2048.
// ---------------------------------------------------------------------------
__global__ __launch_bounds__(256) void qkv_gemm(
    const bf16* __restrict__ A,
    const bf16* __restrict__ B0, const bf16* __restrict__ B1,
    const bf16* __restrict__ B2,
    bf16* __restrict__ C0, bf16* __restrict__ C1, bf16* __restrict__ Cvt,
    const floatx2* __restrict__ rtab,
    int M, int N, int K)
{
  __shared__ bf16 As[128 * 32];
  __shared__ bf16 Bs[128 * 32];

  const int sel = blockIdx.y >> 4;
  const long m0 = (long)blockIdx.x * 128;
  const long n0 = (long)(blockIdx.y & 15) * 128;
  const bf16* B = (sel == 0) ? B0 : ((sel == 1) ? B1 : B2);

  floatx4 acc[4][4];
  gemm_core(A, B, K, m0, n0, As, Bs, acc);

  const int tid  = threadIdx.x;
  const int wave = tid >> 6;
  const int lane = tid & 63;
  const int quad = lane >> 4;
  const int l16  = lane & 15;
  const int wr = (wave >> 1) * 64;
  const int wc = (wave & 1) * 64;

  if (sel < 2) {
    // RoPE epilogue: pairs (2p,2p+1) live in adjacent lanes (l16 bit0);
    // cos/sin from the precomputed table (s is quad-uniform -> 64B/quad).
    bf16* C = (sel == 0) ? C0 : C1;
    const float sgn = (l16 & 1) ? 1.0f : -1.0f;
#pragma unroll
    for (int ni = 0; ni < 4; ni++) {
      const int n = (int)n0 + wc + ni * 16 + l16;   // h*128 + d
      const int p = (n & 127) >> 1;
#pragma unroll
      for (int mi = 0; mi < 4; mi++) {
        floatx4 v = acc[mi][ni];
        const int mbase = (int)m0 + wr + mi * 16 + quad * 4;
#pragma unroll
        for (int r = 0; r < 4; r++) {
          const int spos = (mbase + r) & 2047;
          const floatx2 cssn = rtab[spos * 64 + p];
          const float pv = dpp_f<0xB1>(v[r]);       // pair partner
          const float outv = v[r] * cssn[0] + pv * (sgn * cssn[1]);
          st(&C[(long)(mbase + r) * N + n], outv);
        }
      }
    }
  } else {
    // transposed V epilogue: v_t[((b*16+h)*128+d)*2048 + s], 4 s packed
#pragma unroll
    for (int ni = 0; ni < 4; ni++) {
      const int n = (int)n0 + wc + ni * 16 + l16;   // h*128 + d
      const int hh = n >> 7, d = n & 127;
#pragma unroll
      for (int mi = 0; mi < 4; mi++) {
        floatx4 v = acc[mi][ni];
        const int m = (int)m0 + wr + mi * 16 + quad * 4;
        const int bb = m >> 11, s = m & 2047;
        unsigned long long pk =
            (unsigned long long)(unsigned short)f2b(v[0]) |
            ((unsigned long long)(unsigned short)f2b(v[1]) << 16) |
            ((unsigned long long)(unsigned short)f2b(v[2]) << 32) |
            ((unsigned long long)(unsigned short)f2b(v[3]) << 48);
        *(unsigned long long*)(Cvt + ((long)((bb * 16 + hh) * 128 + d)) * 2048 + s) = pk;
      }
    }
  }
}

// ---------------------------------------------------------------------------
// Final projection GEMM (bf16 x bf16 -> fp32 out).
// ---------------------------------------------------------------------------
__global__ __launch_bounds__(256) void gemm_out(
    const bf16* __restrict__ A, const bf16* __restrict__ B,
    float* __restrict__ C, int M, int N, int K)
{
  __shared__ bf16 As[128 * 32];
  __shared__ bf16 Bs[128 * 32];
  const long m0 = (long)blockIdx.x * 128;
  const long n0 = (long)blockIdx.y * 128;

  floatx4 acc[4][4];
  gemm_core(A, B, K, m0, n0, As, Bs, acc);

  const int tid  = threadIdx.x;
  const int wave = tid >> 6;
  const int lane = tid & 63;
  const int quad = lane >> 4;
  const int l16  = lane & 15;
  const int wr = (wave >> 1) * 64;
  const int wc = (wave & 1) * 64;

#pragma unroll
  for (int mi = 0; mi < 4; mi++)
#pragma unroll
    for (int ni = 0; ni < 4; ni++) {
      floatx4 v = acc[mi][ni];
      const long row = m0 + wr + mi * 16 + quad * 4;
      const long col = n0 + wc + ni * 16 + l16;
#pragma unroll
      for (int r = 0; r < 4; r++)
        C[(row + r) * (long)N + col] = v[r];
    }
}

// ---------------------------------------------------------------------------
// Causal flash attention. Q-tile 128/block (wave owns 32 rows), kv-tile 64.
// K and V^T staged in LDS with a register software pipeline (tile i+1's
// global loads issue after tile i's staging barrier). DPP softmax, exp2
// domain, heavy-tiles-first. q,k,o layout (B,S,H,hd); vt layout [b*H+h][d][s].
// ---------------------------------------------------------------------------
#define NEG_BIG (-30000.0f)

__global__ __launch_bounds__(256) void flash_attn(
    const bf16* __restrict__ q, const bf16* __restrict__ k,
    const bf16* __restrict__ vt, bf16* __restrict__ o, int S)
{
  __shared__ bf16 Ks[64 * 136];      // K tile row-major, stride 136
  __shared__ bf16 Vt[128 * 72];      // V^T tile: [d][kv], stride 72
  __shared__ bf16 Ps[4][32 * 72];    // per-wave P scratch, stride 72

  const int tid  = threadIdx.x;
  const int wave = tid >> 6;
  const int lane = tid & 63;
  const int quad = lane >> 4;
  const int l16  = lane & 15;

  const int bh = blockIdx.x;
  const int b  = bh >> 4, h = bh & 15;
  const int q0 = ((int)gridDim.y - 1 - (int)blockIdx.y) * 128;  // heavy first

  const bf16* Qb = q + ((long)b * S * 16 + h) * 128;
  const bf16* Kb = k + ((long)b * S * 16 + h) * 128;
  const bf16* Vg = vt + (long)bh * 128 * S;       // [d][s]
  bf16*       Ob = o + ((long)b * S * 16 + h) * 128;

  int kr[4], kc[4], vr[4], vc[4];
#pragma unroll
  for (int it = 0; it < 4; it++) {
    const int c = tid + it * 256;
    kr[it] = c >> 4;  kc[it] = (c & 15) * 8;   // K: 64 rows x 128 d
    vr[it] = c >> 3;  vc[it] = (c & 7) * 8;    // V^T: 128 d x 64 kv
  }

  short8 aq[2][4];
#pragma unroll
  for (int mi = 0; mi < 2; mi++)
#pragma unroll
    for (int kt = 0; kt < 4; kt++)
      aq[mi][kt] = *(const short8*)(
          Qb + (long)(q0 + wave * 32 + mi * 16 + l16) * 2048 + kt * 32 + quad * 8);

  float m_i[2][4], l_i[2][4];
  floatx4 oacc[2][8];
  const floatx4 zero4 = {0.f, 0.f, 0.f, 0.f};
#pragma unroll
  for (int mi = 0; mi < 2; mi++) {
#pragma unroll
    for (int r = 0; r < 4; r++) { m_i[mi][r] = NEG_BIG; l_i[mi][r] = 0.f; }
#pragma unroll
    for (int dt = 0; dt < 8; dt++) oacc[mi][dt] = zero4;
  }

  const float SCL2 = 0.08838834764831845f * 1.4426950408889634f;  // scale*log2e
  const int wrow0 = q0 + wave * 32;
  const int last  = q0 + 64;

  short8 kreg[4], vreg[4];
#pragma unroll
  for (int it = 0; it < 4; it++) {
    kreg[it] = *(const short8*)(Kb + (long)kr[it] * 2048 + kc[it]);
    vreg[it] = *(const short8*)(Vg + (long)vr[it] * S + vc[it]);
  }

  for (int kt0 = 0; kt0 <= last; kt0 += 64) {
    __syncthreads();

#pragma unroll
    for (int it = 0; it < 4; it++) {
      *(short8*)(Ks + kr[it] * 136 + kc[it]) = kreg[it];
      *(short8*)(Vt + vr[it] * 72 + vc[it]) = vreg[it];
    }
    __syncthreads();

    if (kt0 < last) {
      const int n0 = kt0 + 64;
#pragma unroll
      for (int it = 0; it < 4; it++) {
        kreg[it] = *(const short8*)(Kb + (long)(n0 + kr[it]) * 2048 + kc[it]);
        vreg[it] = *(const short8*)(Vg + (long)vr[it] * S + n0 + vc[it]);
      }
    }

    if (kt0 <= wrow0 + 31) {
      floatx4 sc[2][4];
#pragma unroll
      for (int mi = 0; mi < 2; mi++)
#pragma unroll
        for (int nt = 0; nt < 4; nt++) sc[mi][nt] = zero4;
#pragma unroll
      for (int nt = 0; nt < 4; nt++)
#pragma unroll
        for (int kt = 0; kt < 4; kt++) {
          short8 bk = *(const short8*)(Ks + (nt * 16 + l16) * 136 + kt * 32 + quad * 8);
          sc[0][nt] = __builtin_amdgcn_mfma_f32_16x16x32_bf16(aq[0][kt], bk, sc[0][nt], 0, 0, 0);
          sc[1][nt] = __builtin_amdgcn_mfma_f32_16x16x32_bf16(aq[1][kt], bk, sc[1][nt], 0, 0, 0);
        }

      const bool needmask = (kt0 + 63 > wrow0);
      float alpha[2][4];
#pragma unroll
      for (int mi = 0; mi < 2; mi++) {
#pragma unroll
        for (int r = 0; r < 4; r++) {
          const int qr = wrow0 + mi * 16 + quad * 4 + r;
          float mx = NEG_BIG;
          if (needmask) {
#pragma unroll
            for (int nt = 0; nt < 4; nt++) {
              const int kc2 = kt0 + nt * 16 + l16;
              float vsc = sc[mi][nt][r] * SCL2;
              vsc = (kc2 <= qr) ? vsc : NEG_BIG;
              sc[mi][nt][r] = vsc;
              mx = fmaxf(mx, vsc);
            }
          } else {
#pragma unroll
            for (int nt = 0; nt < 4; nt++) {
              float vsc = sc[mi][nt][r] * SCL2;
              sc[mi][nt][r] = vsc;
              mx = fmaxf(mx, vsc);
            }
          }
          mx = red16_max(mx);
          const float mnew = fmaxf(m_i[mi][r], mx);

          alpha[mi][r] = exp2f(m_i[mi][r] - mnew);
          float rs = 0.f;
#pragma unroll
          for (int nt = 0; nt < 4; nt++) {
            float p = exp2f(sc[mi][nt][r] - mnew);
            sc[mi][nt][r] = p;
            rs += p;
          }
          rs = red16_sum(rs);
          l_i[mi][r] = l_i[mi][r] * alpha[mi][r] + rs;
          m_i[mi][r] = mnew;
        }
      }

#pragma unroll
      for (int mi = 0; mi < 2; mi++)
#pragma unroll
        for (int nt = 0; nt < 4; nt++)
#pragma unroll
          for (int r = 0; r < 4; r++)
            Ps[wave][(mi * 16 + quad * 4 + r) * 72 + nt * 16 + l16] =
                __float2bfloat16(sc[mi][nt][r]);

#pragma unroll
      for (int mi = 0; mi < 2; mi++)
#pragma unroll
        for (int dt = 0; dt < 8; dt++)
#pragma unroll
          for (int r = 0; r < 4; r++)
            oacc[mi][dt][r] *= alpha[mi][r];

#pragma unroll
      for (int ks = 0; ks < 2; ks++) {
        short8 ap0 = *(const short8*)(&Ps[wave][(l16) * 72 + ks * 32 + quad * 8]);
        short8 ap1 = *(const short8*)(&Ps[wave][(16 + l16) * 72 + ks * 32 + quad * 8]);
#pragma unroll
        for (int dt = 0; dt < 8; dt++) {
          short8 bv = *(const short8*)(Vt + (dt * 16 + l16) * 72 + ks * 32 + quad * 8);
          oacc[0][dt] = __builtin_amdgcn_mfma_f32_16x16x32_bf16(ap0, bv, oacc[0][dt], 0, 0, 0);
          oacc[1][dt] = __builtin_amdgcn_mfma_f32_16x16x32_bf16(ap1, bv, oacc[1][dt], 0, 0, 0);
        }
      }
    }
  }

#pragma unroll
  for (int mi = 0; mi < 2; mi++)
#pragma unroll
    for (int r = 0; r < 4; r++) {
      const float inv = 1.0f / l_i[mi][r];
      const long s = q0 + wave * 32 + mi * 16 + quad * 4 + r;
#pragma unroll
      for (int dt = 0; dt < 8; dt++)
        Ob[s * 2048 + dt * 16 + l16] = __float2bfloat16(oacc[mi][dt][r] * inv);
    }
}

// ---------------------------------------------------------------------------
extern "C" void kernel_launch(void* const* d_in, const int* in_sizes, int n_in,
                              void* d_out, int out_size, void* d_ws, size_t ws_size,
                              hipStream_t stream) {
  const float* x  = (const float*)d_in[0];
  const float* wq = (const float*)d_in[1];
  const float* wk = (const float*)d_in[2];
  const float* wv = (const float*)d_in[3];
  const float* wo = (const float*)d_in[4];
  float* out = (float*)d_out;

  const int B = 2, S = 2048, D = 2048, H = 16;
  const int M = B * S;                    // 4096
  const long tsz = (long)M * D;           // 8.39M elems
  const long wsz = (long)D * D;           // 4.19M elems

  if (ws_size < 4 * (size_t)tsz * sizeof(bf16)) return;   // 67 MB

  bf16* qb  = (bf16*)d_ws;
  bf16* kb  = qb + tsz;
  bf16* vtb = kb + tsz;                   // transposed V: [b][h][d][s]
  bf16* ab  = vtb + tsz;

  // d_out as scratch: xb (tsz) + wq' (wsz) + wk' (wsz) = exactly out bytes.
  bf16* xb  = (bf16*)d_out;
  bf16* wqb = xb + tsz;
  bf16* wkb = wqb + wsz;
  bf16* wvb = ab;                         // front half of ab (dead until flash)
  floatx2* rtab = (floatx2*)(ab + wsz);   // 1 MB rope table in ab's back half
  bf16* wob = qb;                         // qb dead after flash

  cast_kernel<<<(int)(tsz / 8 / 256), 256, 0, stream>>>(x,  xb,  tsz);
  cast_kernel<<<(int)(wsz / 8 / 256), 256, 0, stream>>>(wq, wqb, wsz);
  cast_kernel<<<(int)(wsz / 8 / 256), 256, 0, stream>>>(wk, wkb, wsz);
  cast_kernel<<<(int)(wsz / 8 / 256), 256, 0, stream>>>(wv, wvb, wsz);
  rope_tab_kernel<<<(S * 64) / 256, 256, 0, stream>>>(rtab);

  qkv_gemm<<<dim3(M / 128, 48), 256, 0, stream>>>(
      xb, wqb, wkb, wvb, qb, kb, vtb, rtab, M, D, D);

  flash_attn<<<dim3(B * H, S / 128), 256, 0, stream>>>(qb, kb, vtb, ab, S);

  cast_kernel<<<(int)(wsz / 8 / 256), 256, 0, stream>>>(wo, wob, wsz);
  gemm_out<<<dim3(M / 128, D / 128), 256, 0, stream>>>(ab, wob, out, M, D, D);
}